// Round 1
// baseline (239.237 us; speedup 1.0000x reference)
//
#include <hip/hip_runtime.h>
#include <cstddef>

#define HH 512
#define WW 512
#define BB 8
#define T  32

// ws layout (floats): [0..72)   keff_edge  (3*3 spatial)*8ch   (depthwise∘pointwise, exact)
//                     [72..193) Keff11     11*11               (curve0∘curve1∘Σcurve2, composed)

__global__ __launch_bounds__(256) void precompute_kernels(
    const float* __restrict__ kd,   // (3,3,1,8)
    const float* __restrict__ kp,   // (1,1,8,8)
    const float* __restrict__ k0,   // (5,5,1,8)
    const float* __restrict__ k1,   // (5,5,8,8)
    const float* __restrict__ k2,   // (3,3,8,16)
    float* __restrict__ ws) {
  __shared__ float k9[648];   // Keff9[(a*9+b)*8 + c1]  (curve0∘curve1)
  __shared__ float k2s[72];   // Σ_c2 k2[(t*3+v)*8+c1]
  const int tid = threadIdx.x;

  // edges effective kernel: keff[(p*3+q)*8 + c] = Σ_c0 kd[pq,c0] * kp[c0,c]
  for (int idx = tid; idx < 72; idx += 256) {
    int c = idx & 7, pq = idx >> 3;
    float s = 0.f;
    for (int c0 = 0; c0 < 8; ++c0) s = fmaf(kd[pq * 8 + c0], kp[c0 * 8 + c], s);
    ws[idx] = s;
  }
  // k2 summed over its 16 output channels
  for (int idx = tid; idx < 72; idx += 256) {
    int c1 = idx & 7, tv = idx >> 3;
    float s = 0.f;
    for (int c2 = 0; c2 < 16; ++c2) s += k2[(tv * 8 + c1) * 16 + c2];
    k2s[idx] = s;
  }
  // Keff9[a,b,c1] = Σ_{p+r=a, q+s=b, c0} k0[p,q,c0] k1[r,s,c0,c1]   (9x9, 1->8)
  for (int idx = tid; idx < 648; idx += 256) {
    int c1 = idx & 7;
    int ab = idx >> 3;
    int a = ab / 9, b = ab % 9;
    float s = 0.f;
    int plo = a > 4 ? a - 4 : 0, phi = a < 4 ? a : 4;
    int qlo = b > 4 ? b - 4 : 0, qhi = b < 4 ? b : 4;
    for (int p = plo; p <= phi; ++p)
      for (int q = qlo; q <= qhi; ++q) {
        int r = a - p, sx = b - q;
        const float* k0p = &k0[(p * 5 + q) * 8];
        const float* k1p = &k1[((r * 5 + sx) * 8) * 8 + c1];
        for (int c0 = 0; c0 < 8; ++c0) s = fmaf(k0p[c0], k1p[c0 * 8], s);
      }
    k9[idx] = s;
  }
  __syncthreads();
  // Keff11[A,B] = Σ_{t+a=A, v+b=B, c1} Keff9[a,b,c1] k2s[t,v,c1]   (11x11, 1->1)
  for (int idx = tid; idx < 121; idx += 256) {
    int A = idx / 11, B = idx % 11;
    float s = 0.f;
    int tlo = A > 8 ? A - 8 : 0, thi = A < 2 ? A : 2;
    int vlo = B > 8 ? B - 8 : 0, vhi = B < 2 ? B : 2;
    for (int t = tlo; t <= thi; ++t)
      for (int v = vlo; v <= vhi; ++v) {
        int a = A - t, b = B - v;
        for (int c1 = 0; c1 < 8; ++c1)
          s = fmaf(k9[(a * 9 + b) * 8 + c1], k2s[(t * 3 + v) * 8 + c1], s);
      }
    ws[72 + idx] = s;
  }
}

// Fused main kernel: one 32x32 output tile per block, 256 threads.
__global__ __launch_bounds__(256) void forcing_main(
    const float* __restrict__ u, const float* __restrict__ img,
    const float* __restrict__ kx, const float* __restrict__ ky,
    const float* __restrict__ sm, const float* __restrict__ kk,
    const float* __restrict__ ws, float* __restrict__ out) {
  __shared__ float su[46][47];   // u tile, radius-7 halo (5 for Keff11 + 2 for smoother)
  __shared__ float se[34][35];   // edges tile, radius-1 halo (for 3x3 grad convs)
  __shared__ float sk[36][37];   // (kappa_pre * kappa_kernel) tile, radius-2 halo
  __shared__ float w_edge[72];
  __shared__ float w_kx[288];
  __shared__ float w_ky[288];
  __shared__ float w_k11[121];
  __shared__ float w_sm[25];

  const int bx = blockIdx.x * T;
  const int by = blockIdx.y * T;
  const int b  = blockIdx.z;
  const int tid = threadIdx.x;
  const float* ub = u   + (size_t)b * HH * WW;
  const float* ib = img + (size_t)b * HH * WW;

  // ---- stage weights + u halo tile ----
  for (int i = tid; i < 72; i += 256)  w_edge[i] = ws[i];
  for (int i = tid; i < 121; i += 256) w_k11[i]  = ws[72 + i];
  for (int i = tid; i < 288; i += 256) { w_kx[i] = kx[i]; w_ky[i] = ky[i]; }
  if (tid < 25) w_sm[tid] = sm[tid];

  for (int idx = tid; idx < 46 * 46; idx += 256) {
    int i = idx / 46, j = idx % 46;
    int gy = by - 7 + i, gx = bx - 7 + j;
    float v = 0.f;
    if ((unsigned)gy < HH && (unsigned)gx < WW) v = ub[gy * WW + gx];
    su[i][j] = v;
  }
  __syncthreads();

  // ---- edges tile: softsign(Σ_c relu(conv3x3(image, keff_edge)))  on (T+2)^2 ----
  for (int idx = tid; idx < 34 * 34; idx += 256) {
    int i = idx / 34, j = idx % 34;          // edge pos (by-1+i, bx-1+j)
    int gy = by - 1 + i, gx = bx - 1 + j;
    float val = 0.f;
    if ((unsigned)gy < HH && (unsigned)gx < WW) {
      float acc[8] = {0.f, 0.f, 0.f, 0.f, 0.f, 0.f, 0.f, 0.f};
      #pragma unroll
      for (int p = 0; p < 3; ++p) {
        int yy = gy + p - 1;
        #pragma unroll
        for (int q = 0; q < 3; ++q) {
          int xx = gx + q - 1;
          float v = 0.f;
          if ((unsigned)yy < HH && (unsigned)xx < WW) v = ib[yy * WW + xx];
          const float* wp = &w_edge[(p * 3 + q) * 8];
          #pragma unroll
          for (int c = 0; c < 8; ++c) acc[c] = fmaf(v, wp[c], acc[c]);
        }
      }
      float e = 0.f;
      #pragma unroll
      for (int c = 0; c < 8; ++c) e += fmaxf(acc[c], 0.f);
      val = e / (1.f + e);                    // soft_sign, e >= 0
    }
    se[i][j] = val;
  }

  // ---- kappa_pre tile: (conv11x11(u, Keff11)) * kappa_kernel  on (T+4)^2 ----
  // strips of 4 along x to amortize weight reads: 36 rows * 9 strips = 324
  for (int idx = tid; idx < 36 * 9; idx += 256) {
    int i = idx / 9, js = (idx % 9) * 4;     // pos (by-2+i, bx-2+js..+3)
    float o0 = 0.f, o1 = 0.f, o2 = 0.f, o3 = 0.f;
    #pragma unroll
    for (int A = 0; A < 11; ++A) {
      float r[14];
      #pragma unroll
      for (int t = 0; t < 14; ++t) r[t] = su[i + A][js + t];
      #pragma unroll
      for (int B2 = 0; B2 < 11; ++B2) {
        float w = w_k11[A * 11 + B2];
        o0 = fmaf(r[B2],     w, o0);
        o1 = fmaf(r[B2 + 1], w, o1);
        o2 = fmaf(r[B2 + 2], w, o2);
        o3 = fmaf(r[B2 + 3], w, o3);
      }
    }
    int gy = by - 2 + i;
    float o[4] = {o0, o1, o2, o3};
    #pragma unroll
    for (int t = 0; t < 4; ++t) {
      int gx = bx - 2 + js + t;
      float val = 0.f;
      if ((unsigned)gy < HH && (unsigned)gx < WW) val = o[t] * kk[gy * WW + gx];
      sk[i][js + t] = val;
    }
  }
  __syncthreads();

  // ---- final: grads (32ch relu-sum) + smoother + combine; 1x4 px strip per thread ----
  {
    const int oy = tid >> 3;
    const int ox = (tid & 7) * 4;
    const int gy = by + oy;
    const int gx = bx + ox;

    // edges 3x6 window covering the 4 pixels' 3x3 neighborhoods
    float e[3][6];
    #pragma unroll
    for (int p = 0; p < 3; ++p)
      #pragma unroll
      for (int t = 0; t < 6; ++t) e[p][t] = se[oy + p][ox + t];

    float gxa[4] = {0.f, 0.f, 0.f, 0.f};
    float gya[4] = {0.f, 0.f, 0.f, 0.f};
    for (int c = 0; c < 32; ++c) {
      float sx[4] = {0.f, 0.f, 0.f, 0.f};
      float sy[4] = {0.f, 0.f, 0.f, 0.f};
      #pragma unroll
      for (int p = 0; p < 3; ++p)
        #pragma unroll
        for (int q = 0; q < 3; ++q) {
          float wxv = w_kx[(p * 3 + q) * 32 + c];
          float wyv = w_ky[(p * 3 + q) * 32 + c];
          #pragma unroll
          for (int t = 0; t < 4; ++t) {
            sx[t] = fmaf(e[p][q + t], wxv, sx[t]);
            sy[t] = fmaf(e[p][q + t], wyv, sy[t]);
          }
        }
      #pragma unroll
      for (int t = 0; t < 4; ++t) {
        gxa[t] += fmaxf(sx[t], 0.f);
        gya[t] += fmaxf(sy[t], 0.f);
      }
    }

    float res[4];
    #pragma unroll
    for (int t = 0; t < 4; ++t) {
      // smoother 5x5 over sk
      float kap = 0.f;
      #pragma unroll
      for (int m = 0; m < 5; ++m)
        #pragma unroll
        for (int n = 0; n < 5; ++n)
          kap = fmaf(sk[oy + m][ox + t + n], w_sm[m * 5 + n], kap);

      float uc = su[oy + 7][ox + 7 + t];
      float xp = uc - su[oy + 7][ox + 6 + t];   // u[y,x] - u[y,x-1]
      float yp = uc - su[oy + 8][ox + 7 + t];   // u[y,x] - u[y+1,x]
      float ec = se[oy + 1][ox + 1 + t];
      // fxn, fyn are identically 0 (grads are sums of relus >= 0)
      res[t] = uc + gxa[t] * xp + gya[t] * yp + ec + kap;
    }

    float4 r4 = make_float4(res[0], res[1], res[2], res[3]);
    *reinterpret_cast<float4*>(&out[((size_t)b * HH + gy) * WW + gx]) = r4;
  }
}

extern "C" void kernel_launch(void* const* d_in, const int* in_sizes, int n_in,
                              void* d_out, int out_size, void* d_ws, size_t ws_size,
                              hipStream_t stream) {
  const float* u   = (const float*)d_in[0];
  const float* img = (const float*)d_in[1];
  const float* kx  = (const float*)d_in[2];
  const float* ky  = (const float*)d_in[3];
  const float* kd  = (const float*)d_in[4];
  const float* kp  = (const float*)d_in[5];
  const float* k0  = (const float*)d_in[6];
  const float* k1  = (const float*)d_in[7];
  const float* k2  = (const float*)d_in[8];
  const float* sm  = (const float*)d_in[9];
  const float* kk  = (const float*)d_in[10];
  float* out = (float*)d_out;
  float* ws  = (float*)d_ws;

  precompute_kernels<<<1, 256, 0, stream>>>(kd, kp, k0, k1, k2, ws);
  dim3 grid(WW / T, HH / T, BB);
  forcing_main<<<grid, 256, 0, stream>>>(u, img, kx, ky, sm, kk, ws, out);
}